// Round 3
// baseline (600.290 us; speedup 1.0000x reference)
//
#include <hip/hip_runtime.h>
#include <hip/hip_bf16.h>

#define BN 16
#define LL 2048
#define DD 256
#define BM 32
#define BJ 64

// Block: 256 threads = 4 waves. Wave rtid owns rows [rtid*8, rtid*8+8); lane ctid owns
// cols [ctid*4, ctid*4+4). All score/emb LDS reads in the matmul are wave-uniform
// broadcasts (conflict-free); writes are stride-1.
__global__ __launch_bounds__(256, 2)
void tpp_fused(const float* __restrict__ et,     // event_time [B,L] f32
               const float* __restrict__ noise,  // [B,L,D] f32
               const float* __restrict__ gp,     // [2] f32
               const float* __restrict__ lsc,    // [1] f32
               const float* __restrict__ Wn,     // [D,D] f32
               const float* __restrict__ Wi,     // [D,D] f32
               const float* __restrict__ wt,     // [D] f32
               const float* __restrict__ bt,     // [1] f32
               const float* __restrict__ gam,    // [D] f32
               const float* __restrict__ bet,    // [D] f32
               float* __restrict__ out)          // [B,L] f32
{
    __shared__ __align__(16) float sS[BM][BJ];
    __shared__ float tIs[BM];
    __shared__ float tJs[BJ];
    __shared__ __align__(16) float X[BM][512];   // [noise(256) | hidden_ln(256)]

    const int tid  = threadIdx.x;
    const int rtid = tid >> 6;   // wave id 0..3
    const int ctid = tid & 63;   // lane 0..63

    const int bidx  = blockIdx.x;
    const int b     = bidx & (BN - 1);
    const int itile = (LL / BM - 1) - (bidx >> 4);  // heaviest blocks first
    const int i0    = itile * BM;

    // ---- scalars ----
    const float gp0 = gp[0];
    const float gp1 = gp[1];
    const float lgt = 1.0f / (1.0f + __expf(-gp0));          // l = sigmoid(gp0)
    const float sgt = 1.0f / (1.0f + __expf(-gp1));          // s = sigmoid(gp1)
    const float lsv = lsc[0];
    const float ls  = log1pf(__expf(lsv));                   // softplus(length_scale)
    const float inv_ls2 = 1.0f / (ls * ls);
    const float inv_T   = 1.0f / 200.0f;
    const float inv_s2  = 2.0f / sgt;                        // folded "2/s" for gate

    // per-thread column constants: ipv[c] = 10000^(-2 d / 256), d = ctid*4+c
    const int d0 = ctid * 4;
    float ipv[4];
#pragma unroll
    for (int c = 0; c < 4; ++c)
        ipv[c] = __expf(-(float)(d0 + c) * 0.0719557841532429f);  // 2*ln(1e4)/256

    // ---- stage noise rows into X[.][0..255] ----
    {
        const float* nptr = noise + ((size_t)b * LL + i0) * DD;
        for (int idx = tid; idx < BM * (DD / 4); idx += 256) {
            int row = idx >> 6;      // 64 x float4 chunks per row
            int c4  = idx & 63;
            float4 u = *(const float4*)(nptr + (size_t)row * DD + c4 * 4);
            *(float4*)&X[row][c4 * 4] = u;
        }
    }

    if (tid < BM) tIs[tid] = et[(size_t)b * LL + i0 + tid];

    float acc[8][4];
#pragma unroll
    for (int r = 0; r < 8; ++r)
#pragma unroll
        for (int c = 0; c < 4; ++c) acc[r][c] = 0.0f;

    // ---- scores @ emb, causal j-tiles ----
    const int ntile = ((i0 + BM - 1) >> 6) + 1;
    for (int jt = 0; jt < ntile; ++jt) {
        const int j0 = jt * BJ;
        if (tid < BJ) tJs[tid] = et[(size_t)b * LL + j0 + tid];
        __syncthreads();

        // score tile: 8 (i,j) pairs per thread: i = p*4+rtid, j = ctid
#pragma unroll
        for (int p = 0; p < 8; ++p) {
            int i  = p * 4 + rtid;
            float dt = fabsf(tIs[i] - tJs[ctid]);
            float kk = __expf(-dt * dt * inv_ls2);
            float x2 = (dt * inv_T - lgt) * inv_s2;           // 2*(dt/T - l)/s
            float gate = 2.0f / (1.0f + __expf(-x2));         // 1 + tanh(y)
            float sc = kk * gate;
            if (i0 + i < j0 + ctid) sc = 0.0f;                // causal mask (j<=i kept)
            sS[i][ctid] = sc;
        }
        __syncthreads();

        // matmul: acc[r][c] += sS[row][j] * emb(t_j, d0+c)
        for (int jq = 0; jq < BJ / 4; ++jq) {
            float em[4][4];
#pragma unroll
            for (int jj = 0; jj < 4; ++jj) {
                float tj = tJs[jq * 4 + jj];
                em[jj][0] = __sinf(tj * ipv[0]);
                em[jj][1] = __cosf(tj * ipv[1]);
                em[jj][2] = __sinf(tj * ipv[2]);
                em[jj][3] = __cosf(tj * ipv[3]);
            }
#pragma unroll
            for (int r = 0; r < 8; ++r) {
                float4 sv = *(const float4*)&sS[rtid * 8 + r][jq * 4];
#pragma unroll
                for (int c = 0; c < 4; ++c) {
                    acc[r][c] += sv.x * em[0][c];
                    acc[r][c] += sv.y * em[1][c];
                    acc[r][c] += sv.z * em[2][c];
                    acc[r][c] += sv.w * em[3][c];
                }
            }
        }
        __syncthreads();
    }

    // ---- LayerNorm (wave-level: each wave owns 8 full rows) ----
    {
        float g4[4], be4[4];
#pragma unroll
        for (int c = 0; c < 4; ++c) {
            g4[c]  = gam[d0 + c];
            be4[c] = bet[d0 + c];
        }
#pragma unroll
        for (int r = 0; r < 8; ++r) {
            float s1 = acc[r][0] + acc[r][1] + acc[r][2] + acc[r][3];
            float s2 = acc[r][0]*acc[r][0] + acc[r][1]*acc[r][1]
                     + acc[r][2]*acc[r][2] + acc[r][3]*acc[r][3];
#pragma unroll
            for (int off = 1; off < 64; off <<= 1) {
                s1 += __shfl_xor(s1, off, 64);
                s2 += __shfl_xor(s2, off, 64);
            }
            float mu   = s1 * (1.0f / 256.0f);
            float var  = s2 * (1.0f / 256.0f) - mu * mu;
            float rstd = rsqrtf(var + 1e-6f);
            float4 xv;
            xv.x = (acc[r][0] - mu) * rstd * g4[0] + be4[0];
            xv.y = (acc[r][1] - mu) * rstd * g4[1] + be4[1];
            xv.z = (acc[r][2] - mu) * rstd * g4[2] + be4[2];
            xv.w = (acc[r][3] - mu) * rstd * g4[3] + be4[3];
            *(float4*)&X[rtid * 8 + r][256 + d0] = xv;
        }
    }
    __syncthreads();

    // ---- generator: h = relu(noise@WnT + hidden@WiT) ----
#pragma unroll
    for (int r = 0; r < 8; ++r)
#pragma unroll
        for (int c = 0; c < 4; ++c) acc[r][c] = 0.0f;

    for (int half = 0; half < 2; ++half) {
        const float* W = (half == 0) ? Wn : Wi;
        const int xoff = half * 256;
        for (int k4 = 0; k4 < 64; ++k4) {
            const int k = k4 * 4;
            float xr[8][4];
#pragma unroll
            for (int r = 0; r < 8; ++r) {
                float4 xv = *(const float4*)&X[rtid * 8 + r][xoff + k];
                xr[r][0] = xv.x; xr[r][1] = xv.y; xr[r][2] = xv.z; xr[r][3] = xv.w;
            }
#pragma unroll
            for (int c = 0; c < 4; ++c) {
                float4 w = *(const float4*)(W + (size_t)(d0 + c) * DD + k);
#pragma unroll
                for (int r = 0; r < 8; ++r)
                    acc[r][c] += xr[r][0]*w.x + xr[r][1]*w.y + xr[r][2]*w.z + xr[r][3]*w.w;
            }
        }
    }

    // ---- epilogue: softplus(relu(h) . w_time + b_time) ----
    {
        float wt4[4];
#pragma unroll
        for (int c = 0; c < 4; ++c) wt4[c] = wt[d0 + c];
        const float btv = bt[0];
#pragma unroll
        for (int r = 0; r < 8; ++r) {
            float p = 0.0f;
#pragma unroll
            for (int c = 0; c < 4; ++c) {
                float hv = acc[r][c] > 0.0f ? acc[r][c] : 0.0f;
                p += hv * wt4[c];
            }
#pragma unroll
            for (int off = 1; off < 64; off <<= 1) p += __shfl_xor(p, off, 64);
            if (ctid == 0) {
                float z  = p + btv;
                float sp = (z > 20.0f) ? z : log1pf(__expf(z));
                out[(size_t)b * LL + i0 + rtid * 8 + r] = sp;
            }
        }
    }
}

extern "C" void kernel_launch(void* const* d_in, const int* in_sizes, int n_in,
                              void* d_out, int out_size, void* d_ws, size_t ws_size,
                              hipStream_t stream) {
    (void)in_sizes; (void)n_in; (void)d_ws; (void)ws_size; (void)out_size;
    const float* et    = (const float*)d_in[1];
    const float* noise = (const float*)d_in[2];
    const float* gp    = (const float*)d_in[3];
    const float* lsc   = (const float*)d_in[4];
    const float* Wn    = (const float*)d_in[5];
    const float* Wi    = (const float*)d_in[6];
    const float* wt    = (const float*)d_in[7];
    const float* bt    = (const float*)d_in[8];
    const float* gam   = (const float*)d_in[9];
    const float* bet   = (const float*)d_in[10];
    float* out = (float*)d_out;

    dim3 grid(BN * (LL / BM));
    tpp_fused<<<grid, dim3(256), 0, stream>>>(et, noise, gp, lsc, Wn, Wi, wt, bt,
                                              gam, bet, out);
}

// Round 6
// 486.916 us; speedup vs baseline: 1.2328x; 1.2328x over previous
//
#include <hip/hip_runtime.h>

#define BN 16
#define LL 2048
#define DD 256

typedef __attribute__((ext_vector_type(8))) short bf16x8;
typedef __attribute__((ext_vector_type(4))) float f32x4;

__device__ __forceinline__ unsigned int f2bf1(float f) {
    union { float f; unsigned int i; } v; v.f = f;
    return (v.i + 0x7fffu + ((v.i >> 16) & 1u)) >> 16;
}
__device__ __forceinline__ float bfval(unsigned int h) {
    union { unsigned int i; float f; } v; v.i = h << 16;
    return v.f;
}
__device__ __forceinline__ unsigned int pk2bf(float a, float b) {
    return f2bf1(a) | (f2bf1(b) << 16);
}

// BISECT KERNEL: stage 1 = MFMA hi/lo (round-5 path under test),
// stage 2 + epilogue = round-3-proven fp32 VALU path (no prep_w, no d_ws).
__global__ __launch_bounds__(256, 2)
void tpp_bisect(const float* __restrict__ et,
                const float* __restrict__ noise,
                const float* __restrict__ gp,
                const float* __restrict__ lsc,
                const float* __restrict__ Wn,
                const float* __restrict__ Wi,
                const float* __restrict__ wt,
                const float* __restrict__ bt,
                const float* __restrict__ gam,
                const float* __restrict__ bet,
                float* __restrict__ out) {
    __shared__ __align__(16) unsigned short sA[4 * 64 * 8];   // score hi A-frags
    __shared__ __align__(16) unsigned short sAl[4 * 64 * 8];  // score lo A-frags
    __shared__ float tIs[32];
    __shared__ float tJs[64];
    __shared__ __align__(16) float X[32][512];   // [noise(0..255) | hidden(256..511)]

    const int tid = threadIdx.x;
    const int w   = tid >> 6;    // wave 0..3
    const int ln  = tid & 63;    // lane
    const int qd  = ln >> 4;     // quad 0..3
    const int n16 = ln & 15;

    const int bidx  = blockIdx.x;
    const int b     = bidx & (BN - 1);
    const int itile = 63 - (bidx >> 4);       // heaviest blocks first
    const int i0    = itile * 32;

    // ---- scalars ----
    const float lgt = 1.0f / (1.0f + __expf(-gp[0]));
    const float sgt = 1.0f / (1.0f + __expf(-gp[1]));
    const float ls  = log1pf(__expf(lsc[0]));
    const float inv_ls2 = 1.0f / (ls * ls);
    const float inv_T   = 1.0f / 200.0f;
    const float inv_s2  = 2.0f / sgt;

    // stage-1 emb per-lane constants: d = w*64 + cg*16 + n16
    float ipv4[4];
#pragma unroll
    for (int cg = 0; cg < 4; ++cg)
        ipv4[cg] = __expf(-(float)(w * 64 + cg * 16 + n16) * 0.0719557841532429f);
    const float offl = (n16 & 1) ? 1.57079632679489662f : 0.0f;  // cos = sin(x+pi/2)

    // ---- noise -> X[.][0..255] (fp32, coalesced), tIs ----
    {
        const float* nptr = noise + ((size_t)b * LL + i0) * DD;
        for (int idx = tid; idx < 32 * 64; idx += 256) {
            int row = idx >> 6, c4 = idx & 63;
            *(float4*)&X[row][c4 * 4] = *(const float4*)(nptr + (size_t)row * DD + c4 * 4);
        }
    }
    if (tid < 32) tIs[tid] = et[(size_t)b * LL + i0 + tid];

    // score-thread mapping: t -> (m, g, quad, ks)
    const int sm  = tid & 15;
    const int sg  = (tid >> 4) & 1;
    const int sqd = (tid >> 5) & 3;
    const int sks = tid >> 7;

    f32x4 acc[2][4];
#pragma unroll
    for (int g = 0; g < 2; ++g)
#pragma unroll
        for (int cg = 0; cg < 4; ++cg) {
            f32x4 z = {0.f, 0.f, 0.f, 0.f};
            acc[g][cg] = z;
        }

    // ---- stage 1: causal j-tiles of 64, bf16 MFMA with hi/lo compensation ----
    const int ntile = (i0 >> 6) + 1;
    for (int jt = 0; jt < ntile; ++jt) {
        const int j0 = jt * 64;
        __syncthreads();   // protect sA/sAl/tJs reuse; also covers noise/tIs staging at jt=0
        if (tid < 64) tJs[tid] = et[(size_t)b * LL + j0 + tid];

        {
            const float* etb = et + (size_t)b * LL + j0 + sks * 32 + sqd * 8;
            float ti = tIs[sg * 16 + sm];
            int gi = i0 + sg * 16 + sm;
            int jb = j0 + sks * 32 + sqd * 8;
            unsigned int hb[8];
            float lo[8];
#pragma unroll
            for (int jj = 0; jj < 8; ++jj) {
                float tj = etb[jj];
                float dt = fabsf(ti - tj);
                float kk = __expf(-dt * dt * inv_ls2);
                float x2 = (dt * inv_T - lgt) * inv_s2;
                float gate = __fdividef(2.0f, 1.0f + __expf(-x2));
                float s = kk * gate;
                if (gi < jb + jj) s = 0.0f;
                hb[jj] = f2bf1(s);
                lo[jj] = s - bfval(hb[jj]);
            }
            int base = ((sks * 2 + sg) * 64 + sqd * 16 + sm) * 8;
            uint4 rh, rl;
            rh.x = hb[0] | (hb[1] << 16); rh.y = hb[2] | (hb[3] << 16);
            rh.z = hb[4] | (hb[5] << 16); rh.w = hb[6] | (hb[7] << 16);
            rl.x = pk2bf(lo[0], lo[1]); rl.y = pk2bf(lo[2], lo[3]);
            rl.z = pk2bf(lo[4], lo[5]); rl.w = pk2bf(lo[6], lo[7]);
            *(uint4*)&sA[base]  = rh;
            *(uint4*)&sAl[base] = rl;
        }
        __syncthreads();

#pragma unroll
        for (int ks = 0; ks < 2; ++ks) {
            bf16x8 a0h = *(const bf16x8*)&sA[((ks * 2 + 0) * 64 + ln) * 8];
            bf16x8 a1h = *(const bf16x8*)&sA[((ks * 2 + 1) * 64 + ln) * 8];
            bf16x8 a0l = *(const bf16x8*)&sAl[((ks * 2 + 0) * 64 + ln) * 8];
            bf16x8 a1l = *(const bf16x8*)&sAl[((ks * 2 + 1) * 64 + ln) * 8];
            float tj[8];
#pragma unroll
            for (int jj = 0; jj < 8; ++jj) tj[jj] = tJs[ks * 32 + qd * 8 + jj];
#pragma unroll
            for (int cg = 0; cg < 4; ++cg) {
                unsigned int eh[8];
                float el[8];
#pragma unroll
                for (int jj = 0; jj < 8; ++jj) {
                    float e = __sinf(fmaf(tj[jj], ipv4[cg], offl));
                    eh[jj] = f2bf1(e);
                    el[jj] = e - bfval(eh[jj]);
                }
                union { uint4 u; bf16x8 v; } bh, bl;
                bh.u.x = eh[0] | (eh[1] << 16); bh.u.y = eh[2] | (eh[3] << 16);
                bh.u.z = eh[4] | (eh[5] << 16); bh.u.w = eh[6] | (eh[7] << 16);
                bl.u.x = pk2bf(el[0], el[1]); bl.u.y = pk2bf(el[2], el[3]);
                bl.u.z = pk2bf(el[4], el[5]); bl.u.w = pk2bf(el[6], el[7]);
                acc[0][cg] = __builtin_amdgcn_mfma_f32_16x16x32_bf16(a0h, bh.v, acc[0][cg], 0, 0, 0);
                acc[0][cg] = __builtin_amdgcn_mfma_f32_16x16x32_bf16(a0l, bh.v, acc[0][cg], 0, 0, 0);
                acc[0][cg] = __builtin_amdgcn_mfma_f32_16x16x32_bf16(a0h, bl.v, acc[0][cg], 0, 0, 0);
                acc[1][cg] = __builtin_amdgcn_mfma_f32_16x16x32_bf16(a1h, bh.v, acc[1][cg], 0, 0, 0);
                acc[1][cg] = __builtin_amdgcn_mfma_f32_16x16x32_bf16(a1l, bh.v, acc[1][cg], 0, 0, 0);
                acc[1][cg] = __builtin_amdgcn_mfma_f32_16x16x32_bf16(a1h, bl.v, acc[1][cg], 0, 0, 0);
            }
        }
    }

    // ---- dump C-frags -> X[row][256+col] (row = g*16+qd*4+reg, col = w*64+cg*16+n16) ----
    __syncthreads();
#pragma unroll
    for (int g = 0; g < 2; ++g)
#pragma unroll
        for (int cg = 0; cg < 4; ++cg)
#pragma unroll
            for (int reg = 0; reg < 4; ++reg)
                X[g * 16 + qd * 4 + reg][256 + w * 64 + cg * 16 + n16] = acc[g][cg][reg];
    __syncthreads();

    // ---- LayerNorm in place on X[.][256..511] (wave w owns rows w*8..w*8+7) ----
    {
        float4 gv = *(const float4*)(gam + ln * 4);
        float4 bv = *(const float4*)(bet + ln * 4);
#pragma unroll
        for (int r = 0; r < 8; ++r) {
            int row = w * 8 + r;
            float4 xv = *(const float4*)&X[row][256 + ln * 4];
            float s1 = xv.x + xv.y + xv.z + xv.w;
            float s2 = xv.x * xv.x + xv.y * xv.y + xv.z * xv.z + xv.w * xv.w;
#pragma unroll
            for (int off = 1; off < 64; off <<= 1) {
                s1 += __shfl_xor(s1, off, 64);
                s2 += __shfl_xor(s2, off, 64);
            }
            float mu   = s1 * (1.0f / 256.0f);
            float var  = s2 * (1.0f / 256.0f) - mu * mu;
            float rstd = rsqrtf(var + 1e-6f);
            float4 yv;
            yv.x = (xv.x - mu) * rstd * gv.x + bv.x;
            yv.y = (xv.y - mu) * rstd * gv.y + bv.y;
            yv.z = (xv.z - mu) * rstd * gv.z + bv.z;
            yv.w = (xv.w - mu) * rstd * gv.w + bv.w;
            *(float4*)&X[row][256 + ln * 4] = yv;
        }
    }
    __syncthreads();

    // ---- stage 2 (round-3 proven fp32 VALU): h = relu(noise@WnT + hidden@WiT) ----
    const int d0 = ln * 4;
    float acc2[8][4];
#pragma unroll
    for (int r = 0; r < 8; ++r)
#pragma unroll
        for (int c = 0; c < 4; ++c) acc2[r][c] = 0.0f;

    for (int half = 0; half < 2; ++half) {
        const float* W = (half == 0) ? Wn : Wi;
        const int xoff = half * 256;
        for (int k4 = 0; k4 < 64; ++k4) {
            const int k = k4 * 4;
            float xr[8][4];
#pragma unroll
            for (int r = 0; r < 8; ++r) {
                float4 xv = *(const float4*)&X[w * 8 + r][xoff + k];
                xr[r][0] = xv.x; xr[r][1] = xv.y; xr[r][2] = xv.z; xr[r][3] = xv.w;
            }
#pragma unroll
            for (int c = 0; c < 4; ++c) {
                float4 wv = *(const float4*)(W + (size_t)(d0 + c) * DD + k);
#pragma unroll
                for (int r = 0; r < 8; ++r)
                    acc2[r][c] += xr[r][0]*wv.x + xr[r][1]*wv.y + xr[r][2]*wv.z + xr[r][3]*wv.w;
            }
        }
    }

    // ---- epilogue (round-3 proven): softplus(relu(h) . w_time + b_time) ----
    {
        float wt4[4];
#pragma unroll
        for (int c = 0; c < 4; ++c) wt4[c] = wt[d0 + c];
        const float btv = bt[0];
#pragma unroll
        for (int r = 0; r < 8; ++r) {
            float p = 0.0f;
#pragma unroll
            for (int c = 0; c < 4; ++c) {
                float hv = acc2[r][c] > 0.0f ? acc2[r][c] : 0.0f;
                p += hv * wt4[c];
            }
#pragma unroll
            for (int off = 1; off < 64; off <<= 1) p += __shfl_xor(p, off, 64);
            if (ln == 0) {
                float z  = p + btv;
                float sp = (z > 20.0f) ? z : log1pf(__expf(z));
                out[(size_t)b * LL + i0 + w * 8 + r] = sp;
            }
        }
    }
}

extern "C" void kernel_launch(void* const* d_in, const int* in_sizes, int n_in,
                              void* d_out, int out_size, void* d_ws, size_t ws_size,
                              hipStream_t stream) {
    (void)in_sizes; (void)n_in; (void)out_size; (void)d_ws; (void)ws_size;
    const float* et    = (const float*)d_in[1];
    const float* noise = (const float*)d_in[2];
    const float* gp    = (const float*)d_in[3];
    const float* lsc   = (const float*)d_in[4];
    const float* Wn    = (const float*)d_in[5];
    const float* Wi    = (const float*)d_in[6];
    const float* wt    = (const float*)d_in[7];
    const float* bt    = (const float*)d_in[8];
    const float* gam   = (const float*)d_in[9];
    const float* bet   = (const float*)d_in[10];
    float* out = (float*)d_out;

    tpp_bisect<<<dim3(BN * 64), dim3(256), 0, stream>>>(et, noise, gp, lsc, Wn, Wi,
                                                        wt, bt, gam, bet, out);
}

// Round 7
// 274.068 us; speedup vs baseline: 2.1903x; 1.7766x over previous
//
#include <hip/hip_runtime.h>

#define BN 16
#define LL 2048
#define DD 256
#define XS 516   // padded row stride for X (floats); 516%8==0 -> float4-aligned rows

typedef __attribute__((ext_vector_type(8))) short bf16x8;
typedef __attribute__((ext_vector_type(4))) float f32x4;

__device__ __forceinline__ unsigned int f2bf1(float f) {
    union { float f; unsigned int i; } v; v.f = f;
    return (v.i + 0x7fffu + ((v.i >> 16) & 1u)) >> 16;
}
__device__ __forceinline__ float bfval(unsigned int h) {
    union { unsigned int i; float f; } v; v.i = h << 16;
    return v.f;
}
__device__ __forceinline__ unsigned int pk2bf(float a, float b) {
    return f2bf1(a) | (f2bf1(b) << 16);
}

// 256 threads = 4 waves. Stage 1: hidden = (k*gate*mask) @ emb via bf16 MFMA
// with hi/lo compensation (bisect-proven). Stage 2: generator GEMM via bf16
// MFMA — A-frags straight from fp32 LDS, B-frags straight from global W
// (L2-hot), C dumped with the stage-1-proven pattern. No workspace.
__global__ __launch_bounds__(256, 2)
void tpp_mfma2(const float* __restrict__ et,
               const float* __restrict__ noise,
               const float* __restrict__ gp,
               const float* __restrict__ lsc,
               const float* __restrict__ Wn,
               const float* __restrict__ Wi,
               const float* __restrict__ wt,
               const float* __restrict__ bt,
               const float* __restrict__ gam,
               const float* __restrict__ bet,
               float* __restrict__ out) {
    __shared__ __align__(16) unsigned short sA[4 * 64 * 8];   // score hi A-frags
    __shared__ __align__(16) unsigned short sAl[4 * 64 * 8];  // score lo A-frags
    __shared__ float tIs[32];
    __shared__ float tJs[64];
    __shared__ __align__(16) float X[32][XS];  // cols 0..255 noise, 256..511 hidden/h

    const int tid = threadIdx.x;
    const int w   = tid >> 6;    // wave 0..3
    const int ln  = tid & 63;    // lane
    const int qd  = ln >> 4;     // quad 0..3
    const int n16 = ln & 15;

    const int bidx  = blockIdx.x;
    const int b     = bidx & (BN - 1);
    const int itile = 63 - (bidx >> 4);       // heaviest blocks first
    const int i0    = itile * 32;

    // ---- scalars ----
    const float lgt = 1.0f / (1.0f + __expf(-gp[0]));
    const float sgt = 1.0f / (1.0f + __expf(-gp[1]));
    const float ls  = log1pf(__expf(lsc[0]));
    const float inv_ls2 = 1.0f / (ls * ls);
    const float inv_T   = 1.0f / 200.0f;
    const float inv_s2  = 2.0f / sgt;

    // stage-1 emb per-lane constants: d = w*64 + cg*16 + n16
    float ipv4[4];
#pragma unroll
    for (int cg = 0; cg < 4; ++cg)
        ipv4[cg] = __expf(-(float)(w * 64 + cg * 16 + n16) * 0.0719557841532429f);
    const float offl = (n16 & 1) ? 1.57079632679489662f : 0.0f;  // cos = sin(x+pi/2)

    // ---- noise -> X[.][0..255] (fp32, coalesced), tIs ----
    {
        const float* nptr = noise + ((size_t)b * LL + i0) * DD;
        for (int idx = tid; idx < 32 * 64; idx += 256) {
            int row = idx >> 6, c4 = idx & 63;
            *(float4*)&X[row][c4 * 4] = *(const float4*)(nptr + (size_t)row * DD + c4 * 4);
        }
    }
    if (tid < 32) tIs[tid] = et[(size_t)b * LL + i0 + tid];

    // score-thread mapping: t -> (m, g, quad, ks)
    const int sm  = tid & 15;
    const int sg  = (tid >> 4) & 1;
    const int sqd = (tid >> 5) & 3;
    const int sks = tid >> 7;

    f32x4 acc[2][4];
#pragma unroll
    for (int g = 0; g < 2; ++g)
#pragma unroll
        for (int cg = 0; cg < 4; ++cg) {
            f32x4 z = {0.f, 0.f, 0.f, 0.f};
            acc[g][cg] = z;
        }

    // ---- stage 1: causal j-tiles of 64, bf16 MFMA with hi/lo compensation ----
    const int ntile = (i0 >> 6) + 1;
    for (int jt = 0; jt < ntile; ++jt) {
        const int j0 = jt * 64;
        __syncthreads();   // protects sA/sAl/tJs reuse; covers noise/tIs staging at jt=0
        if (tid < 64) tJs[tid] = et[(size_t)b * LL + j0 + tid];

        {
            const float* etb = et + (size_t)b * LL + j0 + sks * 32 + sqd * 8;
            float ti = tIs[sg * 16 + sm];
            int gi = i0 + sg * 16 + sm;
            int jb = j0 + sks * 32 + sqd * 8;
            unsigned int hb[8];
            float lo[8];
#pragma unroll
            for (int jj = 0; jj < 8; ++jj) {
                float tj = etb[jj];
                float dt = fabsf(ti - tj);
                float kk = __expf(-dt * dt * inv_ls2);
                float x2 = (dt * inv_T - lgt) * inv_s2;
                float gate = __fdividef(2.0f, 1.0f + __expf(-x2));
                float s = kk * gate;
                if (gi < jb + jj) s = 0.0f;
                hb[jj] = f2bf1(s);
                lo[jj] = s - bfval(hb[jj]);
            }
            int base = ((sks * 2 + sg) * 64 + sqd * 16 + sm) * 8;
            uint4 rh, rl;
            rh.x = hb[0] | (hb[1] << 16); rh.y = hb[2] | (hb[3] << 16);
            rh.z = hb[4] | (hb[5] << 16); rh.w = hb[6] | (hb[7] << 16);
            rl.x = pk2bf(lo[0], lo[1]); rl.y = pk2bf(lo[2], lo[3]);
            rl.z = pk2bf(lo[4], lo[5]); rl.w = pk2bf(lo[6], lo[7]);
            *(uint4*)&sA[base]  = rh;
            *(uint4*)&sAl[base] = rl;
        }
        __syncthreads();

#pragma unroll
        for (int ks = 0; ks < 2; ++ks) {
            bf16x8 a0h = *(const bf16x8*)&sA[((ks * 2 + 0) * 64 + ln) * 8];
            bf16x8 a1h = *(const bf16x8*)&sA[((ks * 2 + 1) * 64 + ln) * 8];
            bf16x8 a0l = *(const bf16x8*)&sAl[((ks * 2 + 0) * 64 + ln) * 8];
            bf16x8 a1l = *(const bf16x8*)&sAl[((ks * 2 + 1) * 64 + ln) * 8];
            float tj[8];
#pragma unroll
            for (int jj = 0; jj < 8; ++jj) tj[jj] = tJs[ks * 32 + qd * 8 + jj];
#pragma unroll
            for (int cg = 0; cg < 4; ++cg) {
                unsigned int eh[8];
                float el[8];
#pragma unroll
                for (int jj = 0; jj < 8; ++jj) {
                    float e = __sinf(fmaf(tj[jj], ipv4[cg], offl));
                    eh[jj] = f2bf1(e);
                    el[jj] = e - bfval(eh[jj]);
                }
                union { uint4 u; bf16x8 v; } bh, bl;
                bh.u.x = eh[0] | (eh[1] << 16); bh.u.y = eh[2] | (eh[3] << 16);
                bh.u.z = eh[4] | (eh[5] << 16); bh.u.w = eh[6] | (eh[7] << 16);
                bl.u.x = pk2bf(el[0], el[1]); bl.u.y = pk2bf(el[2], el[3]);
                bl.u.z = pk2bf(el[4], el[5]); bl.u.w = pk2bf(el[6], el[7]);
                acc[0][cg] = __builtin_amdgcn_mfma_f32_16x16x32_bf16(a0h, bh.v, acc[0][cg], 0, 0, 0);
                acc[0][cg] = __builtin_amdgcn_mfma_f32_16x16x32_bf16(a0l, bh.v, acc[0][cg], 0, 0, 0);
                acc[0][cg] = __builtin_amdgcn_mfma_f32_16x16x32_bf16(a0h, bl.v, acc[0][cg], 0, 0, 0);
                acc[1][cg] = __builtin_amdgcn_mfma_f32_16x16x32_bf16(a1h, bh.v, acc[1][cg], 0, 0, 0);
                acc[1][cg] = __builtin_amdgcn_mfma_f32_16x16x32_bf16(a1l, bh.v, acc[1][cg], 0, 0, 0);
                acc[1][cg] = __builtin_amdgcn_mfma_f32_16x16x32_bf16(a1h, bl.v, acc[1][cg], 0, 0, 0);
            }
        }
    }

    // ---- dump C-frags -> X[row][256+col] (proven pattern) ----
    __syncthreads();
#pragma unroll
    for (int g = 0; g < 2; ++g)
#pragma unroll
        for (int cg = 0; cg < 4; ++cg)
#pragma unroll
            for (int reg = 0; reg < 4; ++reg)
                X[g * 16 + qd * 4 + reg][256 + w * 64 + cg * 16 + n16] = acc[g][cg][reg];
    __syncthreads();

    // ---- LayerNorm in place on X[.][256..511] (wave w owns rows w*8..w*8+7) ----
    {
        float4 gv = *(const float4*)(gam + ln * 4);
        float4 bv = *(const float4*)(bet + ln * 4);
#pragma unroll
        for (int r = 0; r < 8; ++r) {
            int row = w * 8 + r;
            float4 xv = *(const float4*)&X[row][256 + ln * 4];
            float s1 = xv.x + xv.y + xv.z + xv.w;
            float s2 = xv.x * xv.x + xv.y * xv.y + xv.z * xv.z + xv.w * xv.w;
#pragma unroll
            for (int off = 1; off < 64; off <<= 1) {
                s1 += __shfl_xor(s1, off, 64);
                s2 += __shfl_xor(s2, off, 64);
            }
            float mu   = s1 * (1.0f / 256.0f);
            float var  = s2 * (1.0f / 256.0f) - mu * mu;
            float rstd = rsqrtf(var + 1e-6f);
            float4 yv;
            yv.x = (xv.x - mu) * rstd * gv.x + bv.x;
            yv.y = (xv.y - mu) * rstd * gv.y + bv.y;
            yv.z = (xv.z - mu) * rstd * gv.z + bv.z;
            yv.w = (xv.w - mu) * rstd * gv.w + bv.w;
            *(float4*)&X[row][256 + ln * 4] = yv;
        }
    }
    __syncthreads();

    // ---- stage 2: h = relu([noise|hidden] @ [Wn|Wi]^T) via bf16 MFMA ----
    // A-frag: lane holds X[g*16+n16][ks2*32+qd*8 .. +7] (fp32->bf16 in-register).
    // B-frag: lane holds W[(w*4+cg)*16+n16][kw .. kw+7] from global (L2-hot).
    f32x4 acc2[2][4];
#pragma unroll
    for (int g = 0; g < 2; ++g)
#pragma unroll
        for (int cg = 0; cg < 4; ++cg) {
            f32x4 z = {0.f, 0.f, 0.f, 0.f};
            acc2[g][cg] = z;
        }
    for (int ks2 = 0; ks2 < 16; ++ks2) {
        const int kk = ks2 * 32 + qd * 8;          // 0..511
        bf16x8 a[2];
#pragma unroll
        for (int g = 0; g < 2; ++g) {
            const float* xp = &X[g * 16 + n16][kk];
            float4 xa = *(const float4*)xp;
            float4 xc = *(const float4*)(xp + 4);
            union { uint4 u; bf16x8 v; } aa;
            aa.u.x = pk2bf(xa.x, xa.y); aa.u.y = pk2bf(xa.z, xa.w);
            aa.u.z = pk2bf(xc.x, xc.y); aa.u.w = pk2bf(xc.z, xc.w);
            a[g] = aa.v;
        }
        const float* Wbase = (ks2 < 8) ? Wn : Wi;
        const int kw = (ks2 < 8) ? kk : (kk - 256);
#pragma unroll
        for (int cg = 0; cg < 4; ++cg) {
            const int o = (w * 4 + cg) * 16 + n16;
            const float* wp = Wbase + (size_t)o * DD + kw;
            float4 wa = *(const float4*)wp;
            float4 wc = *(const float4*)(wp + 4);
            union { uint4 u; bf16x8 v; } bb;
            bb.u.x = pk2bf(wa.x, wa.y); bb.u.y = pk2bf(wa.z, wa.w);
            bb.u.z = pk2bf(wc.x, wc.y); bb.u.w = pk2bf(wc.z, wc.w);
            acc2[0][cg] = __builtin_amdgcn_mfma_f32_16x16x32_bf16(a[0], bb.v, acc2[0][cg], 0, 0, 0);
            acc2[1][cg] = __builtin_amdgcn_mfma_f32_16x16x32_bf16(a[1], bb.v, acc2[1][cg], 0, 0, 0);
        }
    }

    // ---- dump h C-frags -> X[row][256+col] (same proven pattern) ----
    __syncthreads();
#pragma unroll
    for (int g = 0; g < 2; ++g)
#pragma unroll
        for (int cg = 0; cg < 4; ++cg)
#pragma unroll
            for (int reg = 0; reg < 4; ++reg)
                X[g * 16 + qd * 4 + reg][256 + w * 64 + cg * 16 + n16] = acc2[g][cg][reg];
    __syncthreads();

    // ---- epilogue (round-3-proven shape): softplus(relu(h) . w_time + b_time) ----
    {
        const int d0 = ln * 4;
        float4 wv = *(const float4*)(wt + d0);
        const float btv = bt[0];
#pragma unroll
        for (int r = 0; r < 8; ++r) {
            int row = w * 8 + r;
            float4 hv = *(const float4*)&X[row][256 + d0];
            float p = fmaxf(hv.x, 0.0f) * wv.x + fmaxf(hv.y, 0.0f) * wv.y
                    + fmaxf(hv.z, 0.0f) * wv.z + fmaxf(hv.w, 0.0f) * wv.w;
#pragma unroll
            for (int off = 1; off < 64; off <<= 1) p += __shfl_xor(p, off, 64);
            if (ln == 0) {
                float z  = p + btv;
                float sp = (z > 20.0f) ? z : log1pf(__expf(z));
                out[(size_t)b * LL + i0 + row] = sp;
            }
        }
    }
}

extern "C" void kernel_launch(void* const* d_in, const int* in_sizes, int n_in,
                              void* d_out, int out_size, void* d_ws, size_t ws_size,
                              hipStream_t stream) {
    (void)in_sizes; (void)n_in; (void)out_size; (void)d_ws; (void)ws_size;
    const float* et    = (const float*)d_in[1];
    const float* noise = (const float*)d_in[2];
    const float* gp    = (const float*)d_in[3];
    const float* lsc   = (const float*)d_in[4];
    const float* Wn    = (const float*)d_in[5];
    const float* Wi    = (const float*)d_in[6];
    const float* wt    = (const float*)d_in[7];
    const float* bt    = (const float*)d_in[8];
    const float* gam   = (const float*)d_in[9];
    const float* bet   = (const float*)d_in[10];
    float* out = (float*)d_out;

    tpp_mfma2<<<dim3(BN * 64), dim3(256), 0, stream>>>(et, noise, gp, lsc, Wn, Wi,
                                                       wt, bt, gam, bet, out);
}

// Round 11
// 240.523 us; speedup vs baseline: 2.4958x; 1.1395x over previous
//
#include <hip/hip_runtime.h>

#define BN 16
#define LL 2048
#define DD 256
#define XS 516   // padded row stride for X (floats); 516%4==0 -> float4-aligned rows

typedef __attribute__((ext_vector_type(8))) short bf16x8;
typedef __attribute__((ext_vector_type(4))) float f32x4;

__device__ __forceinline__ unsigned int f2bf1(float f) {
    union { float f; unsigned int i; } v; v.f = f;
    return (v.i + 0x7fffu + ((v.i >> 16) & 1u)) >> 16;
}
__device__ __forceinline__ float bfval(unsigned int h) {
    union { unsigned int i; float f; } v; v.i = h << 16;
    return v.f;
}
__device__ __forceinline__ unsigned int pk2bf(float a, float b) {   // RNE pack
    return f2bf1(a) | (f2bf1(b) << 16);
}

// ROUND-7 GREEN BASE, verbatim layout (X[32][516], fp32 noise staging, separate
// sA/sAl, lb2). Single change vs round 7: emb-lo compensation dropped in the
// stage-1 MFMA phase (scores keep hi+lo; emb is RNE-hi only -> 4 MFMAs/cg-unit
// instead of 6, no el/bl build).
__global__ __launch_bounds__(256, 2)
void tpp_v11(const float* __restrict__ et,
             const float* __restrict__ noise,
             const float* __restrict__ gp,
             const float* __restrict__ lsc,
             const float* __restrict__ Wn,
             const float* __restrict__ Wi,
             const float* __restrict__ wt,
             const float* __restrict__ bt,
             const float* __restrict__ gam,
             const float* __restrict__ bet,
             float* __restrict__ out) {
    __shared__ __align__(16) unsigned short sA[4 * 64 * 8];   // score hi A-frags
    __shared__ __align__(16) unsigned short sAl[4 * 64 * 8];  // score lo A-frags
    __shared__ float tIs[32];
    __shared__ float tJs[64];
    __shared__ __align__(16) float X[32][XS];  // cols 0..255 noise, 256..511 hidden/h

    const int tid = threadIdx.x;
    const int w   = tid >> 6;    // wave 0..3
    const int ln  = tid & 63;    // lane
    const int qd  = ln >> 4;     // quad 0..3
    const int n16 = ln & 15;

    const int bidx  = blockIdx.x;
    const int b     = bidx & (BN - 1);
    const int itile = 63 - (bidx >> 4);       // heaviest blocks first
    const int i0    = itile * 32;

    // ---- scalars ----
    const float lgt = 1.0f / (1.0f + __expf(-gp[0]));
    const float sgt = 1.0f / (1.0f + __expf(-gp[1]));
    const float ls  = log1pf(__expf(lsc[0]));
    const float inv_ls2 = 1.0f / (ls * ls);
    const float inv_T   = 1.0f / 200.0f;
    const float inv_s2  = 2.0f / sgt;

    // stage-1 emb per-lane constants: d = w*64 + cg*16 + n16
    float ipv4[4];
#pragma unroll
    for (int cg = 0; cg < 4; ++cg)
        ipv4[cg] = __expf(-(float)(w * 64 + cg * 16 + n16) * 0.0719557841532429f);
    const float offl = (n16 & 1) ? 1.57079632679489662f : 0.0f;  // cos = sin(x+pi/2)

    // ---- noise -> X[.][0..255] (fp32, coalesced), tIs ----
    {
        const float* nptr = noise + ((size_t)b * LL + i0) * DD;
        for (int idx = tid; idx < 32 * 64; idx += 256) {
            int row = idx >> 6, c4 = idx & 63;
            *(float4*)&X[row][c4 * 4] = *(const float4*)(nptr + (size_t)row * DD + c4 * 4);
        }
    }
    if (tid < 32) tIs[tid] = et[(size_t)b * LL + i0 + tid];

    // score-thread mapping: t -> (m, g, quad, ks)
    const int sm  = tid & 15;
    const int sg  = (tid >> 4) & 1;
    const int sqd = (tid >> 5) & 3;
    const int sks = tid >> 7;

    f32x4 acc[2][4];
#pragma unroll
    for (int g = 0; g < 2; ++g)
#pragma unroll
        for (int cg = 0; cg < 4; ++cg) {
            f32x4 z = {0.f, 0.f, 0.f, 0.f};
            acc[g][cg] = z;
        }

    // ---- stage 1: causal j-tiles of 64, bf16 MFMA, scores hi/lo compensated ----
    const int ntile = (i0 >> 6) + 1;
    for (int jt = 0; jt < ntile; ++jt) {
        const int j0 = jt * 64;
        __syncthreads();   // protects sA/sAl/tJs reuse; covers noise/tIs staging at jt=0
        if (tid < 64) tJs[tid] = et[(size_t)b * LL + j0 + tid];

        {
            const float* etb = et + (size_t)b * LL + j0 + sks * 32 + sqd * 8;
            float ti = tIs[sg * 16 + sm];
            int gi = i0 + sg * 16 + sm;
            int jb = j0 + sks * 32 + sqd * 8;
            unsigned int hb[8];
            float lo[8];
#pragma unroll
            for (int jj = 0; jj < 8; ++jj) {
                float tj = etb[jj];
                float dt = fabsf(ti - tj);
                float kk = __expf(-dt * dt * inv_ls2);
                float x2 = (dt * inv_T - lgt) * inv_s2;
                float gate = __fdividef(2.0f, 1.0f + __expf(-x2));
                float s = kk * gate;
                if (gi < jb + jj) s = 0.0f;
                hb[jj] = f2bf1(s);
                lo[jj] = s - bfval(hb[jj]);
            }
            int base = ((sks * 2 + sg) * 64 + sqd * 16 + sm) * 8;
            uint4 rh, rl;
            rh.x = hb[0] | (hb[1] << 16); rh.y = hb[2] | (hb[3] << 16);
            rh.z = hb[4] | (hb[5] << 16); rh.w = hb[6] | (hb[7] << 16);
            rl.x = pk2bf(lo[0], lo[1]); rl.y = pk2bf(lo[2], lo[3]);
            rl.z = pk2bf(lo[4], lo[5]); rl.w = pk2bf(lo[6], lo[7]);
            *(uint4*)&sA[base]  = rh;
            *(uint4*)&sAl[base] = rl;
        }
        __syncthreads();

        // MFMA phase: scores hi+lo from LDS, emb RNE-hi only (single change vs r7)
#pragma unroll
        for (int ks = 0; ks < 2; ++ks) {
            bf16x8 a0h = *(const bf16x8*)&sA[((ks * 2 + 0) * 64 + ln) * 8];
            bf16x8 a1h = *(const bf16x8*)&sA[((ks * 2 + 1) * 64 + ln) * 8];
            bf16x8 a0l = *(const bf16x8*)&sAl[((ks * 2 + 0) * 64 + ln) * 8];
            bf16x8 a1l = *(const bf16x8*)&sAl[((ks * 2 + 1) * 64 + ln) * 8];
            float tj[8];
#pragma unroll
            for (int jj = 0; jj < 8; ++jj) tj[jj] = tJs[ks * 32 + qd * 8 + jj];
#pragma unroll
            for (int cg = 0; cg < 4; ++cg) {
                unsigned int eh[8];
#pragma unroll
                for (int jj = 0; jj < 8; ++jj) {
                    float e = __sinf(fmaf(tj[jj], ipv4[cg], offl));
                    eh[jj] = f2bf1(e);
                }
                union { uint4 u; bf16x8 v; } bh;
                bh.u.x = eh[0] | (eh[1] << 16); bh.u.y = eh[2] | (eh[3] << 16);
                bh.u.z = eh[4] | (eh[5] << 16); bh.u.w = eh[6] | (eh[7] << 16);
                acc[0][cg] = __builtin_amdgcn_mfma_f32_16x16x32_bf16(a0h, bh.v, acc[0][cg], 0, 0, 0);
                acc[0][cg] = __builtin_amdgcn_mfma_f32_16x16x32_bf16(a0l, bh.v, acc[0][cg], 0, 0, 0);
                acc[1][cg] = __builtin_amdgcn_mfma_f32_16x16x32_bf16(a1h, bh.v, acc[1][cg], 0, 0, 0);
                acc[1][cg] = __builtin_amdgcn_mfma_f32_16x16x32_bf16(a1l, bh.v, acc[1][cg], 0, 0, 0);
            }
        }
    }

    // ---- dump C-frags -> X[row][256+col] (row = g*16+qd*4+reg, col = w*64+cg*16+n16) ----
    __syncthreads();
#pragma unroll
    for (int g = 0; g < 2; ++g)
#pragma unroll
        for (int cg = 0; cg < 4; ++cg)
#pragma unroll
            for (int reg = 0; reg < 4; ++reg)
                X[g * 16 + qd * 4 + reg][256 + w * 64 + cg * 16 + n16] = acc[g][cg][reg];
    __syncthreads();

    // ---- LayerNorm in place on X[.][256..511] (wave w owns rows w*8..w*8+7) ----
    {
        float4 gv = *(const float4*)(gam + ln * 4);
        float4 bv = *(const float4*)(bet + ln * 4);
#pragma unroll
        for (int r = 0; r < 8; ++r) {
            int row = w * 8 + r;
            float4 xv = *(const float4*)&X[row][256 + ln * 4];
            float s1 = xv.x + xv.y + xv.z + xv.w;
            float s2 = xv.x * xv.x + xv.y * xv.y + xv.z * xv.z + xv.w * xv.w;
#pragma unroll
            for (int off = 1; off < 64; off <<= 1) {
                s1 += __shfl_xor(s1, off, 64);
                s2 += __shfl_xor(s2, off, 64);
            }
            float mu   = s1 * (1.0f / 256.0f);
            float var  = s2 * (1.0f / 256.0f) - mu * mu;
            float rstd = rsqrtf(var + 1e-6f);
            float4 yv;
            yv.x = (xv.x - mu) * rstd * gv.x + bv.x;
            yv.y = (xv.y - mu) * rstd * gv.y + bv.y;
            yv.z = (xv.z - mu) * rstd * gv.z + bv.z;
            yv.w = (xv.w - mu) * rstd * gv.w + bv.w;
            *(float4*)&X[row][256 + ln * 4] = yv;
        }
    }
    __syncthreads();

    // ---- stage 2: h = relu([noise|hidden] @ [Wn|Wi]^T) via bf16 MFMA ----
    f32x4 acc2[2][4];
#pragma unroll
    for (int g = 0; g < 2; ++g)
#pragma unroll
        for (int cg = 0; cg < 4; ++cg) {
            f32x4 z = {0.f, 0.f, 0.f, 0.f};
            acc2[g][cg] = z;
        }
    for (int ks2 = 0; ks2 < 16; ++ks2) {
        const int kk = ks2 * 32 + qd * 8;          // 0..511
        bf16x8 a[2];
#pragma unroll
        for (int g = 0; g < 2; ++g) {
            const float* xp = &X[g * 16 + n16][kk];
            float4 xa = *(const float4*)xp;
            float4 xc = *(const float4*)(xp + 4);
            union { uint4 u; bf16x8 v; } aa;
            aa.u.x = pk2bf(xa.x, xa.y); aa.u.y = pk2bf(xa.z, xa.w);
            aa.u.z = pk2bf(xc.x, xc.y); aa.u.w = pk2bf(xc.z, xc.w);
            a[g] = aa.v;
        }
        const float* Wbase = (ks2 < 8) ? Wn : Wi;
        const int kw = (ks2 < 8) ? kk : (kk - 256);
#pragma unroll
        for (int cg = 0; cg < 4; ++cg) {
            const int o = (w * 4 + cg) * 16 + n16;
            const float* wp = Wbase + (size_t)o * DD + kw;
            float4 wa = *(const float4*)wp;
            float4 wc = *(const float4*)(wp + 4);
            union { uint4 u; bf16x8 v; } bb;
            bb.u.x = pk2bf(wa.x, wa.y); bb.u.y = pk2bf(wa.z, wa.w);
            bb.u.z = pk2bf(wc.x, wc.y); bb.u.w = pk2bf(wc.z, wc.w);
            acc2[0][cg] = __builtin_amdgcn_mfma_f32_16x16x32_bf16(a[0], bb.v, acc2[0][cg], 0, 0, 0);
            acc2[1][cg] = __builtin_amdgcn_mfma_f32_16x16x32_bf16(a[1], bb.v, acc2[1][cg], 0, 0, 0);
        }
    }

    // ---- dump h C-frags -> X[row][256+col] (same proven pattern) ----
    __syncthreads();
#pragma unroll
    for (int g = 0; g < 2; ++g)
#pragma unroll
        for (int cg = 0; cg < 4; ++cg)
#pragma unroll
            for (int reg = 0; reg < 4; ++reg)
                X[g * 16 + qd * 4 + reg][256 + w * 64 + cg * 16 + n16] = acc2[g][cg][reg];
    __syncthreads();

    // ---- epilogue: softplus(relu(h) . w_time + b_time) ----
    {
        const int d0 = ln * 4;
        float4 wv = *(const float4*)(wt + d0);
        const float btv = bt[0];
#pragma unroll
        for (int r = 0; r < 8; ++r) {
            int row = w * 8 + r;
            float4 hv = *(const float4*)&X[row][256 + d0];
            float p = fmaxf(hv.x, 0.0f) * wv.x + fmaxf(hv.y, 0.0f) * wv.y
                    + fmaxf(hv.z, 0.0f) * wv.z + fmaxf(hv.w, 0.0f) * wv.w;
#pragma unroll
            for (int off = 1; off < 64; off <<= 1) p += __shfl_xor(p, off, 64);
            if (ln == 0) {
                float z  = p + btv;
                float sp = (z > 20.0f) ? z : log1pf(__expf(z));
                out[(size_t)b * LL + i0 + row] = sp;
            }
        }
    }
}

extern "C" void kernel_launch(void* const* d_in, const int* in_sizes, int n_in,
                              void* d_out, int out_size, void* d_ws, size_t ws_size,
                              hipStream_t stream) {
    (void)in_sizes; (void)n_in; (void)out_size; (void)d_ws; (void)ws_size;
    const float* et    = (const float*)d_in[1];
    const float* noise = (const float*)d_in[2];
    const float* gp    = (const float*)d_in[3];
    const float* lsc   = (const float*)d_in[4];
    const float* Wn    = (const float*)d_in[5];
    const float* Wi    = (const float*)d_in[6];
    const float* wt    = (const float*)d_in[7];
    const float* bt    = (const float*)d_in[8];
    const float* gam   = (const float*)d_in[9];
    const float* bet   = (const float*)d_in[10];
    float* out = (float*)d_out;

    tpp_v11<<<dim3(BN * 64), dim3(256), 0, stream>>>(et, noise, gp, lsc, Wn, Wi,
                                                     wt, bt, gam, bet, out);
}

// Round 14
// 240.108 us; speedup vs baseline: 2.5001x; 1.0017x over previous
//
#include <hip/hip_runtime.h>

#define BN 16
#define LL 2048
#define DD 256
#define XS 516   // padded row stride for X (floats); 516%4==0 -> float4-aligned rows

typedef __attribute__((ext_vector_type(8))) short bf16x8;
typedef __attribute__((ext_vector_type(4))) float f32x4;

__device__ __forceinline__ unsigned int f2bf1(float f) {
    union { float f; unsigned int i; } v; v.f = f;
    return (v.i + 0x7fffu + ((v.i >> 16) & 1u)) >> 16;
}
__device__ __forceinline__ float bfval(unsigned int h) {
    union { unsigned int i; float f; } v; v.i = h << 16;
    return v.f;
}
__device__ __forceinline__ unsigned int pk2bf(float a, float b) {   // RNE pack
    return f2bf1(a) | (f2bf1(b) << 16);
}

// ROUND-11 GREEN KERNEL, restored byte-for-byte. Stage 1: hidden =
// (k*gate*mask) @ emb via bf16 MFMA, scores hi/lo-compensated, emb RNE-hi.
// Stage 2: generator GEMM via bf16 MFMA, in-register operand conversion.
__global__ __launch_bounds__(256, 2)
void tpp_v11(const float* __restrict__ et,
             const float* __restrict__ noise,
             const float* __restrict__ gp,
             const float* __restrict__ lsc,
             const float* __restrict__ Wn,
             const float* __restrict__ Wi,
             const float* __restrict__ wt,
             const float* __restrict__ bt,
             const float* __restrict__ gam,
             const float* __restrict__ bet,
             float* __restrict__ out) {
    __shared__ __align__(16) unsigned short sA[4 * 64 * 8];   // score hi A-frags
    __shared__ __align__(16) unsigned short sAl[4 * 64 * 8];  // score lo A-frags
    __shared__ float tIs[32];
    __shared__ float tJs[64];
    __shared__ __align__(16) float X[32][XS];  // cols 0..255 noise, 256..511 hidden/h

    const int tid = threadIdx.x;
    const int w   = tid >> 6;    // wave 0..3
    const int ln  = tid & 63;    // lane
    const int qd  = ln >> 4;     // quad 0..3
    const int n16 = ln & 15;

    const int bidx  = blockIdx.x;
    const int b     = bidx & (BN - 1);
    const int itile = 63 - (bidx >> 4);       // heaviest blocks first
    const int i0    = itile * 32;

    // ---- scalars ----
    const float lgt = 1.0f / (1.0f + __expf(-gp[0]));
    const float sgt = 1.0f / (1.0f + __expf(-gp[1]));
    const float ls  = log1pf(__expf(lsc[0]));
    const float inv_ls2 = 1.0f / (ls * ls);
    const float inv_T   = 1.0f / 200.0f;
    const float inv_s2  = 2.0f / sgt;

    // stage-1 emb per-lane constants: d = w*64 + cg*16 + n16
    float ipv4[4];
#pragma unroll
    for (int cg = 0; cg < 4; ++cg)
        ipv4[cg] = __expf(-(float)(w * 64 + cg * 16 + n16) * 0.0719557841532429f);
    const float offl = (n16 & 1) ? 1.57079632679489662f : 0.0f;  // cos = sin(x+pi/2)

    // ---- noise -> X[.][0..255] (fp32, coalesced), tIs ----
    {
        const float* nptr = noise + ((size_t)b * LL + i0) * DD;
        for (int idx = tid; idx < 32 * 64; idx += 256) {
            int row = idx >> 6, c4 = idx & 63;
            *(float4*)&X[row][c4 * 4] = *(const float4*)(nptr + (size_t)row * DD + c4 * 4);
        }
    }
    if (tid < 32) tIs[tid] = et[(size_t)b * LL + i0 + tid];

    // score-thread mapping: t -> (m, g, quad, ks)
    const int sm  = tid & 15;
    const int sg  = (tid >> 4) & 1;
    const int sqd = (tid >> 5) & 3;
    const int sks = tid >> 7;

    f32x4 acc[2][4];
#pragma unroll
    for (int g = 0; g < 2; ++g)
#pragma unroll
        for (int cg = 0; cg < 4; ++cg) {
            f32x4 z = {0.f, 0.f, 0.f, 0.f};
            acc[g][cg] = z;
        }

    // ---- stage 1: causal j-tiles of 64, bf16 MFMA, scores hi/lo compensated ----
    const int ntile = (i0 >> 6) + 1;
    for (int jt = 0; jt < ntile; ++jt) {
        const int j0 = jt * 64;
        __syncthreads();   // protects sA/sAl/tJs reuse; covers noise/tIs staging at jt=0
        if (tid < 64) tJs[tid] = et[(size_t)b * LL + j0 + tid];

        {
            const float* etb = et + (size_t)b * LL + j0 + sks * 32 + sqd * 8;
            float ti = tIs[sg * 16 + sm];
            int gi = i0 + sg * 16 + sm;
            int jb = j0 + sks * 32 + sqd * 8;
            unsigned int hb[8];
            float lo[8];
#pragma unroll
            for (int jj = 0; jj < 8; ++jj) {
                float tj = etb[jj];
                float dt = fabsf(ti - tj);
                float kk = __expf(-dt * dt * inv_ls2);
                float x2 = (dt * inv_T - lgt) * inv_s2;
                float gate = __fdividef(2.0f, 1.0f + __expf(-x2));
                float s = kk * gate;
                if (gi < jb + jj) s = 0.0f;
                hb[jj] = f2bf1(s);
                lo[jj] = s - bfval(hb[jj]);
            }
            int base = ((sks * 2 + sg) * 64 + sqd * 16 + sm) * 8;
            uint4 rh, rl;
            rh.x = hb[0] | (hb[1] << 16); rh.y = hb[2] | (hb[3] << 16);
            rh.z = hb[4] | (hb[5] << 16); rh.w = hb[6] | (hb[7] << 16);
            rl.x = pk2bf(lo[0], lo[1]); rl.y = pk2bf(lo[2], lo[3]);
            rl.z = pk2bf(lo[4], lo[5]); rl.w = pk2bf(lo[6], lo[7]);
            *(uint4*)&sA[base]  = rh;
            *(uint4*)&sAl[base] = rl;
        }
        __syncthreads();

        // MFMA phase: scores hi+lo from LDS, emb RNE-hi built in registers
#pragma unroll
        for (int ks = 0; ks < 2; ++ks) {
            bf16x8 a0h = *(const bf16x8*)&sA[((ks * 2 + 0) * 64 + ln) * 8];
            bf16x8 a1h = *(const bf16x8*)&sA[((ks * 2 + 1) * 64 + ln) * 8];
            bf16x8 a0l = *(const bf16x8*)&sAl[((ks * 2 + 0) * 64 + ln) * 8];
            bf16x8 a1l = *(const bf16x8*)&sAl[((ks * 2 + 1) * 64 + ln) * 8];
            float tj[8];
#pragma unroll
            for (int jj = 0; jj < 8; ++jj) tj[jj] = tJs[ks * 32 + qd * 8 + jj];
#pragma unroll
            for (int cg = 0; cg < 4; ++cg) {
                unsigned int eh[8];
#pragma unroll
                for (int jj = 0; jj < 8; ++jj) {
                    float e = __sinf(fmaf(tj[jj], ipv4[cg], offl));
                    eh[jj] = f2bf1(e);
                }
                union { uint4 u; bf16x8 v; } bh;
                bh.u.x = eh[0] | (eh[1] << 16); bh.u.y = eh[2] | (eh[3] << 16);
                bh.u.z = eh[4] | (eh[5] << 16); bh.u.w = eh[6] | (eh[7] << 16);
                acc[0][cg] = __builtin_amdgcn_mfma_f32_16x16x32_bf16(a0h, bh.v, acc[0][cg], 0, 0, 0);
                acc[0][cg] = __builtin_amdgcn_mfma_f32_16x16x32_bf16(a0l, bh.v, acc[0][cg], 0, 0, 0);
                acc[1][cg] = __builtin_amdgcn_mfma_f32_16x16x32_bf16(a1h, bh.v, acc[1][cg], 0, 0, 0);
                acc[1][cg] = __builtin_amdgcn_mfma_f32_16x16x32_bf16(a1l, bh.v, acc[1][cg], 0, 0, 0);
            }
        }
    }

    // ---- dump C-frags -> X[row][256+col] (row = g*16+qd*4+reg, col = w*64+cg*16+n16) ----
    __syncthreads();
#pragma unroll
    for (int g = 0; g < 2; ++g)
#pragma unroll
        for (int cg = 0; cg < 4; ++cg)
#pragma unroll
            for (int reg = 0; reg < 4; ++reg)
                X[g * 16 + qd * 4 + reg][256 + w * 64 + cg * 16 + n16] = acc[g][cg][reg];
    __syncthreads();

    // ---- LayerNorm in place on X[.][256..511] (wave w owns rows w*8..w*8+7) ----
    {
        float4 gv = *(const float4*)(gam + ln * 4);
        float4 bv = *(const float4*)(bet + ln * 4);
#pragma unroll
        for (int r = 0; r < 8; ++r) {
            int row = w * 8 + r;
            float4 xv = *(const float4*)&X[row][256 + ln * 4];
            float s1 = xv.x + xv.y + xv.z + xv.w;
            float s2 = xv.x * xv.x + xv.y * xv.y + xv.z * xv.z + xv.w * xv.w;
#pragma unroll
            for (int off = 1; off < 64; off <<= 1) {
                s1 += __shfl_xor(s1, off, 64);
                s2 += __shfl_xor(s2, off, 64);
            }
            float mu   = s1 * (1.0f / 256.0f);
            float var  = s2 * (1.0f / 256.0f) - mu * mu;
            float rstd = rsqrtf(var + 1e-6f);
            float4 yv;
            yv.x = (xv.x - mu) * rstd * gv.x + bv.x;
            yv.y = (xv.y - mu) * rstd * gv.y + bv.y;
            yv.z = (xv.z - mu) * rstd * gv.z + bv.z;
            yv.w = (xv.w - mu) * rstd * gv.w + bv.w;
            *(float4*)&X[row][256 + ln * 4] = yv;
        }
    }
    __syncthreads();

    // ---- stage 2: h = relu([noise|hidden] @ [Wn|Wi]^T) via bf16 MFMA ----
    f32x4 acc2[2][4];
#pragma unroll
    for (int g = 0; g < 2; ++g)
#pragma unroll
        for (int cg = 0; cg < 4; ++cg) {
            f32x4 z = {0.f, 0.f, 0.f, 0.f};
            acc2[g][cg] = z;
        }
    for (int ks2 = 0; ks2 < 16; ++ks2) {
        const int kk = ks2 * 32 + qd * 8;
        bf16x8 a[2];
#pragma unroll
        for (int g = 0; g < 2; ++g) {
            const float* xp = &X[g * 16 + n16][kk];
            float4 xa = *(const float4*)xp;
            float4 xc = *(const float4*)(xp + 4);
            union { uint4 u; bf16x8 v; } aa;
            aa.u.x = pk2bf(xa.x, xa.y); aa.u.y = pk2bf(xa.z, xa.w);
            aa.u.z = pk2bf(xc.x, xc.y); aa.u.w = pk2bf(xc.z, xc.w);
            a[g] = aa.v;
        }
        const float* Wbase = (ks2 < 8) ? Wn : Wi;
        const int kw = (ks2 < 8) ? kk : (kk - 256);
#pragma unroll
        for (int cg = 0; cg < 4; ++cg) {
            const int o = (w * 4 + cg) * 16 + n16;
            const float* wp = Wbase + (size_t)o * DD + kw;
            float4 wa = *(const float4*)wp;
            float4 wc = *(const float4*)(wp + 4);
            union { uint4 u; bf16x8 v; } bb;
            bb.u.x = pk2bf(wa.x, wa.y); bb.u.y = pk2bf(wa.z, wa.w);
            bb.u.z = pk2bf(wc.x, wc.y); bb.u.w = pk2bf(wc.z, wc.w);
            acc2[0][cg] = __builtin_amdgcn_mfma_f32_16x16x32_bf16(a[0], bb.v, acc2[0][cg], 0, 0, 0);
            acc2[1][cg] = __builtin_amdgcn_mfma_f32_16x16x32_bf16(a[1], bb.v, acc2[1][cg], 0, 0, 0);
        }
    }

    // ---- dump h C-frags -> X[row][256+col] (same proven pattern) ----
    __syncthreads();
#pragma unroll
    for (int g = 0; g < 2; ++g)
#pragma unroll
        for (int cg = 0; cg < 4; ++cg)
#pragma unroll
            for (int reg = 0; reg < 4; ++reg)
                X[g * 16 + qd * 4 + reg][256 + w * 64 + cg * 16 + n16] = acc2[g][cg][reg];
    __syncthreads();

    // ---- epilogue: softplus(relu(h) . w_time + b_time) ----
    {
        const int d0 = ln * 4;
        float4 wv = *(const float4*)(wt + d0);
        const float btv = bt[0];
#pragma unroll
        for (int r = 0; r < 8; ++r) {
            int row = w * 8 + r;
            float4 hv = *(const float4*)&X[row][256 + d0];
            float p = fmaxf(hv.x, 0.0f) * wv.x + fmaxf(hv.y, 0.0f) * wv.y
                    + fmaxf(hv.z, 0.0f) * wv.z + fmaxf(hv.w, 0.0f) * wv.w;
#pragma unroll
            for (int off = 1; off < 64; off <<= 1) p += __shfl_xor(p, off, 64);
            if (ln == 0) {
                float z  = p + btv;
                float sp = (z > 20.0f) ? z : log1pf(__expf(z));
                out[(size_t)b * LL + i0 + row] = sp;
            }
        }
    }
}

extern "C" void kernel_launch(void* const* d_in, const int* in_sizes, int n_in,
                              void* d_out, int out_size, void* d_ws, size_t ws_size,
                              hipStream_t stream) {
    (void)in_sizes; (void)n_in; (void)out_size; (void)d_ws; (void)ws_size;
    const float* et    = (const float*)d_in[1];
    const float* noise = (const float*)d_in[2];
    const float* gp    = (const float*)d_in[3];
    const float* lsc   = (const float*)d_in[4];
    const float* Wn    = (const float*)d_in[5];
    const float* Wi    = (const float*)d_in[6];
    const float* wt    = (const float*)d_in[7];
    const float* bt    = (const float*)d_in[8];
    const float* gam   = (const float*)d_in[9];
    const float* bet   = (const float*)d_in[10];
    float* out = (float*)d_out;

    tpp_v11<<<dim3(BN * 64), dim3(256), 0, stream>>>(et, noise, gp, lsc, Wn, Wi,
                                                     wt, bt, gam, bet, out);
}